// Round 2
// baseline (7175.820 us; speedup 1.0000x reference)
//
#include <hip/hip_runtime.h>
#include <hip/hip_bf16.h>

typedef __hip_bfloat16 bf16;

#define NEGF (-3.402823466e38f)
#define SCALE 0.08838834764831845f  // 128^-0.5

constexpr int S_    = 1024;
constexpr int H_    = 32;
constexpr int KVH_  = 8;
constexpr int DH_   = 128;
constexpr int QKVN  = 6144;   // H*DH + 2*KVH*DH
constexpr int NC_   = 64;     // S/CB
constexpr int CD_   = 2048;   // CB*DH

__device__ __forceinline__ float ldf(const float x)  { return x; }
__device__ __forceinline__ float ldf(const bf16 x)   { return __bfloat162float(x); }
__device__ __forceinline__ void  stf(float* p, float v) { *p = v; }
__device__ __forceinline__ void  stf(bf16*  p, float v) { *p = __float2bfloat16(v); }

// ---------------------------------------------------------------------------
// Generic tiled GEMM:  C[M,N] = act( A[M,K] * B[N,K]^T + bias[N] )
// act: 0=none, 1=relu, 2=sigmoid.  All dims multiples of 16 in this problem.
// ---------------------------------------------------------------------------
template <typename TA, typename TB, typename TC>
__global__ void gemm_tn(const TA* __restrict__ A, const TB* __restrict__ B,
                        TC* __restrict__ C, const float* __restrict__ bias,
                        int M, int N, int K, int act)
{
    __shared__ float As[16][17];
    __shared__ float Bs[16][17];
    const int tx = threadIdx.x, ty = threadIdx.y;
    const int row = blockIdx.y * 16 + ty;      // M index
    const int col = blockIdx.x * 16 + tx;      // N index
    const int brow = blockIdx.x * 16 + ty;     // N index for B staging
    float acc = 0.f;
    for (int k0 = 0; k0 < K; k0 += 16) {
        As[ty][tx] = (row  < M) ? ldf(A[(size_t)row  * K + k0 + tx]) : 0.f;
        Bs[ty][tx] = (brow < N) ? ldf(B[(size_t)brow * K + k0 + tx]) : 0.f;
        __syncthreads();
        #pragma unroll
        for (int kk = 0; kk < 16; ++kk)
            acc += As[ty][kk] * Bs[tx][kk];
        __syncthreads();
    }
    if (row < M && col < N) {
        if (bias) acc += ldf(bias[col]);
        if (act == 1) acc = fmaxf(acc, 0.f);
        else if (act == 2) acc = 1.f / (1.f + expf(-acc));
        stf(C + (size_t)row * N + col, acc);
    }
}

// ---------------------------------------------------------------------------
// ck_in/cv_in: (k + k_pos), (v + v_pos) reshaped to [KVH*NC, CB*DH]
// ---------------------------------------------------------------------------
__global__ void build_cin(const float* __restrict__ qkv,
                          const float* __restrict__ k_pos,
                          const float* __restrict__ v_pos,
                          float* __restrict__ ckin, float* __restrict__ cvin)
{
    int idx = blockIdx.x * blockDim.x + threadIdx.x;       // KVH*S*DH
    if (idx >= KVH_ * S_ * DH_) return;
    int d = idx & 127;
    int s = (idx >> 7) & 1023;
    int h = idx >> 17;
    int c = s >> 4, t = s & 15;
    float kv = qkv[(size_t)s * QKVN + 4096 + h * DH_ + d];
    float vv = qkv[(size_t)s * QKVN + 5120 + h * DH_ + d];
    size_t row = (size_t)h * NC_ + c;
    size_t col = (size_t)t * DH_ + d;
    ckin[row * CD_ + col] = kv + k_pos[(h * 16 + t) * DH_ + d];
    cvin[row * CD_ + col] = vv + v_pos[(h * 16 + t) * DH_ + d];
}

// ---------------------------------------------------------------------------
// ckf/cvf [KVH, 65, DH]:  row 0 = mem_kv, rows 1..64 = compressed body
// ---------------------------------------------------------------------------
__global__ void assemble_c(const float* __restrict__ ckb, const float* __restrict__ cvb,
                           const float* __restrict__ mem_kv,
                           float* __restrict__ ckf, float* __restrict__ cvf)
{
    int idx = blockIdx.x * blockDim.x + threadIdx.x;       // KVH*65*DH
    if (idx >= KVH_ * 65 * DH_) return;
    int d = idx & 127;
    int j = (idx >> 7) % 65;
    int h = idx / (65 * DH_);
    if (j == 0) {
        ckf[idx] = mem_kv[(0 * KVH_ + h) * DH_ + d];
        cvf[idx] = mem_kv[(1 * KVH_ + h) * DH_ + d];
    } else {
        ckf[idx] = ckb[((size_t)h * NC_ + (j - 1)) * DH_ + d];
        cvf[idx] = cvb[((size_t)h * NC_ + (j - 1)) * DH_ + d];
    }
}

// ---------------------------------------------------------------------------
// Compressed attention: one block per (kvh, g, s).  65 keys (mem + 64 blocks).
// Stores masked scores to csim (needed for importance) and c_out [s,h,d].
// ---------------------------------------------------------------------------
__global__ void compress_attn(const float* __restrict__ qkv,
                              const float* __restrict__ ckf,
                              const float* __restrict__ cvf,
                              float* __restrict__ csim, float* __restrict__ cout)
{
    int b = blockIdx.x;
    int s = b & 1023;
    int g = (b >> 10) & 3;
    int h = b >> 12;               // kvh
    int qh = h * 4 + g;
    int tid = threadIdx.x;         // 128 threads
    __shared__ float qrow[128];
    __shared__ float sim[65];
    __shared__ float p[65];
    __shared__ float inv_den;
    qrow[tid] = qkv[(size_t)s * QKVN + qh * DH_ + tid];
    __syncthreads();
    if (tid < 65) {
        const float* krow = ckf + ((size_t)h * 65 + tid) * DH_;
        bool vis = (tid == 0) || (16 * tid - 1 < s);
        float acc = NEGF;
        if (vis) {
            acc = 0.f;
            for (int d = 0; d < 128; ++d) acc += qrow[d] * krow[d];
            acc *= SCALE;
        }
        sim[tid] = acc;
        csim[(((size_t)h * 4 + g) * S_ + s) * 65 + tid] = acc;
    }
    __syncthreads();
    if (tid == 0) {
        float m = sim[0];
        for (int j = 1; j < 65; ++j) m = fmaxf(m, sim[j]);
        float den = 0.f;
        for (int j = 0; j < 65; ++j) { float e = expf(sim[j] - m); p[j] = e; den += e; }
        inv_den = 1.f / den;
    }
    __syncthreads();
    float acc = 0.f;
    for (int j = 0; j < 65; ++j)
        acc += p[j] * cvf[((size_t)h * 65 + j) * DH_ + tid];
    cout[(size_t)s * 4096 + qh * DH_ + tid] = acc * inv_den;
}

// ---------------------------------------------------------------------------
// Importance softmax (with -1e3 sentinel) + top-4 (lax.top_k tie semantics:
// stable, lowest index wins on ties) + append own block.
// One block per (kvh, s), 64 threads (one wave).
// ---------------------------------------------------------------------------
__global__ void importance_topk(const float* __restrict__ csim,
                                int* __restrict__ selidx, int* __restrict__ fsel)
{
    int b = blockIdx.x;
    int s = b & 1023;
    int h = b >> 10;
    int j = threadIdx.x;            // 0..63 -> compressed block j (csim col j+1)
    float v = 0.f;
    for (int g = 0; g < 4; ++g)
        v += csim[(((size_t)h * 4 + g) * S_ + s) * 65 + 1 + j];
    v *= 0.25f;                      // mean over grouped heads (NEG -> -inf, same as jnp)
    float m = v;
    #pragma unroll
    for (int off = 32; off; off >>= 1) m = fmaxf(m, __shfl_xor(m, off));
    m = fmaxf(m, -1e3f);             // sentinel participates in the max
    float e = expf(v - m);
    float den = e;
    #pragma unroll
    for (int off = 32; off; off >>= 1) den += __shfl_xor(den, off);
    den += expf(-1e3f - m);          // sentinel term
    float pv = e / den;
    __shared__ float ps[64];
    ps[j] = pv;
    __syncthreads();
    if (j == 0) {
        size_t base5 = ((size_t)h * S_ + s) * 5;
        size_t base4 = ((size_t)h * S_ + s) * 4;
        for (int t = 0; t < 4; ++t) {
            int bi = 0; float bv = ps[0];
            for (int i = 1; i < 64; ++i)
                if (ps[i] > bv) { bv = ps[i]; bi = i; }   // strict > : lowest idx on tie
            selidx[base5 + t] = bi;
            fsel[base4 + t]   = (bv > 1e-10f) ? 1 : 0;
            ps[bi] = -1.f;
        }
        selidx[base5 + 4] = s >> 4;   // own block
    }
}

// ---------------------------------------------------------------------------
// Interleaved RoPE (theta=10000) applied in place to the q and k slices of qkv.
// ---------------------------------------------------------------------------
__global__ void rope_inplace(float* __restrict__ qkv)
{
    int idx = blockIdx.x * blockDim.x + threadIdx.x;
    const int totq = S_ * H_ * 64;             // q pairs
    const int totk = S_ * KVH_ * 64;           // k pairs
    float* base;
    int p, s;
    if (idx < totq) {
        p = idx & 63; int head = (idx >> 6) & 31; s = idx >> 11;
        base = qkv + (size_t)s * QKVN + head * DH_;
    } else {
        int i2 = idx - totq;
        if (i2 >= totk) return;
        p = i2 & 63; int head = (i2 >> 6) & 7; s = i2 >> 9;
        base = qkv + (size_t)s * QKVN + 4096 + head * DH_;
    }
    float inv = 1.f / powf(10000.f, (float)(2 * p) / 128.f);
    float ang = (float)s * inv;
    float c = cosf(ang), sn = sinf(ang);
    float x0 = base[2 * p], x1 = base[2 * p + 1];
    base[2 * p]     = x0 * c - x1 * sn;
    base[2 * p + 1] = x1 * c + x0 * sn;
}

// ---------------------------------------------------------------------------
// Fine attention: one block per (kvh, g, s).  5 blocks x 16 keys = 80 keys.
// Keys from roped k (in qkv), values from un-roped v.
// ---------------------------------------------------------------------------
__global__ void fine_attn(const float* __restrict__ qkv,
                          const int* __restrict__ selidx, const int* __restrict__ fsel,
                          float* __restrict__ fout)
{
    int b = blockIdx.x;
    int s = b & 1023;
    int g = (b >> 10) & 3;
    int h = b >> 12;
    int qh = h * 4 + g;
    int tid = threadIdx.x;   // 128
    __shared__ float qrow[128];
    __shared__ float sim[80];
    __shared__ float p[80];
    __shared__ int   blk[5];
    __shared__ int   bvis[5];
    __shared__ float inv_den;
    if (tid < 5) {
        blk[tid]  = selidx[((size_t)h * S_ + s) * 5 + tid];
        bvis[tid] = (tid < 4) ? fsel[((size_t)h * S_ + s) * 4 + tid] : 1;
    }
    qrow[tid] = qkv[(size_t)s * QKVN + qh * DH_ + tid];
    __syncthreads();
    if (tid < 80) {
        int bi = tid >> 4, t = tid & 15;
        int pos = blk[bi] * 16 + t;
        bool vis = (bi < 4) ? (bvis[bi] != 0) : (t <= (s & 15));
        float acc = NEGF;
        if (vis) {
            const float* krow = qkv + (size_t)pos * QKVN + 4096 + h * DH_;
            acc = 0.f;
            for (int d = 0; d < 128; ++d) acc += qrow[d] * krow[d];
            acc *= SCALE;
        }
        sim[tid] = acc;
    }
    __syncthreads();
    if (tid == 0) {
        float m = sim[0];
        for (int j = 1; j < 80; ++j) m = fmaxf(m, sim[j]);
        float den = 0.f;
        for (int j = 0; j < 80; ++j) { float e = expf(sim[j] - m); p[j] = e; den += e; }
        inv_den = 1.f / den;
    }
    __syncthreads();
    float acc = 0.f;
    for (int j = 0; j < 80; ++j) {
        int pos = blk[j >> 4] * 16 + (j & 15);
        acc += p[j] * qkv[(size_t)pos * QKVN + 5120 + h * DH_ + tid];
    }
    fout[(size_t)s * 4096 + qh * DH_ + tid] = acc * inv_den;
}

// ---------------------------------------------------------------------------
// Sliding window: equivalent to causal window 0 <= s-j <= 64, j >= 0.
// One block per (head, s).
// ---------------------------------------------------------------------------
__global__ void sliding_attn(const float* __restrict__ qkv, float* __restrict__ sout)
{
    int b = blockIdx.x;
    int s = b & 1023;
    int qh = b >> 10;
    int kvh = qh >> 2;
    int tid = threadIdx.x;   // 128
    __shared__ float qrow[128];
    __shared__ float sim[65];
    __shared__ float p[65];
    __shared__ float inv_den;
    qrow[tid] = qkv[(size_t)s * QKVN + qh * DH_ + tid];
    __syncthreads();
    if (tid < 65) {
        int pos = s - tid;
        float acc = NEGF;
        if (pos >= 0) {
            const float* krow = qkv + (size_t)pos * QKVN + 4096 + kvh * DH_;
            acc = 0.f;
            for (int d = 0; d < 128; ++d) acc += qrow[d] * krow[d];
            acc *= SCALE;
        }
        sim[tid] = acc;
    }
    __syncthreads();
    if (tid == 0) {
        float m = sim[0];
        for (int j = 1; j < 65; ++j) m = fmaxf(m, sim[j]);
        float den = 0.f;
        for (int j = 0; j < 65; ++j) { float e = expf(sim[j] - m); p[j] = e; den += e; }
        inv_den = 1.f / den;
    }
    __syncthreads();
    float acc = 0.f;
    int lim = (s + 1 < 65) ? (s + 1) : 65;
    for (int j = 0; j < lim; ++j)
        acc += p[j] * qkv[(size_t)(s - j) * QKVN + 5120 + kvh * DH_ + tid];
    sout[(size_t)s * 4096 + qh * DH_ + tid] = acc * inv_den;
}

// ---------------------------------------------------------------------------
// gated combine: cout <- g0*cout + g1*fout + g2*sout   (layout [s, h*128+d])
// ---------------------------------------------------------------------------
__global__ void combine_gate(float* __restrict__ cout, const float* __restrict__ fout,
                             const float* __restrict__ sout, const float* __restrict__ gates)
{
    int idx = blockIdx.x * blockDim.x + threadIdx.x;   // S*4096
    if (idx >= S_ * 4096) return;
    int h = (idx >> 7) & 31;
    int s = idx >> 12;
    float g0 = gates[(size_t)s * 96 + h * 3 + 0];
    float g1 = gates[(size_t)s * 96 + h * 3 + 1];
    float g2 = gates[(size_t)s * 96 + h * 3 + 2];
    cout[idx] = g0 * cout[idx] + g1 * fout[idx] + g2 * sout[idx];
}

// ---------------------------------------------------------------------------
extern "C" void kernel_launch(void* const* d_in, const int* in_sizes, int n_in,
                              void* d_out, int out_size, void* d_ws, size_t ws_size,
                              hipStream_t stream)
{
    // Reference setup_inputs() is pure float32 -> all inputs & output are fp32.
    const float* hidden = (const float*)d_in[0];
    const float* w_qkv  = (const float*)d_in[1];
    const float* w_o    = (const float*)d_in[2];
    const float* k_pos  = (const float*)d_in[3];
    const float* v_pos  = (const float*)d_in[4];
    const float* k_w1   = (const float*)d_in[5];
    const float* k_b1   = (const float*)d_in[6];
    const float* k_w2   = (const float*)d_in[7];
    const float* k_b2   = (const float*)d_in[8];
    const float* v_w1   = (const float*)d_in[9];
    const float* v_b1   = (const float*)d_in[10];
    const float* v_w2   = (const float*)d_in[11];
    const float* v_b2   = (const float*)d_in[12];
    const float* mem_kv = (const float*)d_in[13];
    const float* w_gate = (const float*)d_in[14];
    const float* b_gate = (const float*)d_in[15];
    float* out = (float*)d_out;

    float* ws = (float*)d_ws;
    size_t o = 0;
    float* qkv    = ws + o; o += (size_t)S_ * QKVN;        // 6291456
    float* ckin   = ws + o; o += (size_t)512 * CD_;        // 1048576
    float* cvin   = ws + o; o += (size_t)512 * CD_;
    float* h1     = ws + o; o += (size_t)512 * CD_;
    float* ckb    = ws + o; o += (size_t)512 * DH_;
    float* cvb    = ws + o; o += (size_t)512 * DH_;
    float* ckf    = ws + o; o += (size_t)KVH_ * 65 * DH_;
    float* cvf    = ws + o; o += (size_t)KVH_ * 65 * DH_;
    float* csim   = ws + o; o += (size_t)KVH_ * 4 * S_ * 65;
    float* coutb  = ws + o; o += (size_t)S_ * 4096;
    float* foutb  = ws + o; o += (size_t)S_ * 4096;
    float* soutb  = ws + o; o += (size_t)S_ * 4096;
    float* gatesb = ws + o; o += (size_t)S_ * 96;
    int*   selidx = (int*)(ws + o); o += (size_t)KVH_ * S_ * 5;
    int*   fsel   = (int*)(ws + o); o += (size_t)KVH_ * S_ * 4;

    dim3 blk16(16, 16);

    // 1. qkv projection: [1024,6144] = hidden[1024,4096] @ w_qkv^T
    gemm_tn<float, float, float><<<dim3(QKVN / 16, S_ / 16), blk16, 0, stream>>>(
        hidden, w_qkv, qkv, nullptr, S_, QKVN, 4096, 0);

    // 2. gates: sigmoid(hidden @ w_gate^T + b_gate)  [1024,96]
    gemm_tn<float, float, float><<<dim3(96 / 16, S_ / 16), blk16, 0, stream>>>(
        hidden, w_gate, gatesb, b_gate, S_, 96, 4096, 2);

    // 3. compress inputs
    build_cin<<<(KVH_ * S_ * DH_ + 255) / 256, 256, 0, stream>>>(qkv, k_pos, v_pos, ckin, cvin);

    // 4-7. compress MLPs (K path then V path, sharing h1)
    gemm_tn<float, float, float><<<dim3(CD_ / 16, 512 / 16), blk16, 0, stream>>>(
        ckin, k_w1, h1, k_b1, 512, CD_, CD_, 1);
    gemm_tn<float, float, float><<<dim3(DH_ / 16, 512 / 16), blk16, 0, stream>>>(
        h1, k_w2, ckb, k_b2, 512, DH_, CD_, 0);
    gemm_tn<float, float, float><<<dim3(CD_ / 16, 512 / 16), blk16, 0, stream>>>(
        cvin, v_w1, h1, v_b1, 512, CD_, CD_, 1);
    gemm_tn<float, float, float><<<dim3(DH_ / 16, 512 / 16), blk16, 0, stream>>>(
        h1, v_w2, cvb, v_b2, 512, DH_, CD_, 0);

    // 8. prepend mem token
    assemble_c<<<(KVH_ * 65 * DH_ + 255) / 256, 256, 0, stream>>>(ckb, cvb, mem_kv, ckf, cvf);

    // 9. compressed attention (also writes masked csim for importance)
    compress_attn<<<KVH_ * 4 * S_, 128, 0, stream>>>(qkv, ckf, cvf, csim, coutb);

    // 10. importance + top-k selection
    importance_topk<<<KVH_ * S_, 64, 0, stream>>>(csim, selidx, fsel);

    // 11. RoPE in place on q and k slices of qkv
    {
        int tot = S_ * H_ * 64 + S_ * KVH_ * 64;
        rope_inplace<<<(tot + 255) / 256, 256, 0, stream>>>(qkv);
    }

    // 12. fine (selected-block) attention
    fine_attn<<<KVH_ * 4 * S_, 128, 0, stream>>>(qkv, selidx, fsel, foutb);

    // 13. sliding-window attention
    sliding_attn<<<H_ * S_, 128, 0, stream>>>(qkv, soutb);

    // 14. gated combine into coutb
    combine_gate<<<(S_ * 4096 + 255) / 256, 256, 0, stream>>>(coutb, foutb, soutb, gatesb);

    // 15. output projection -> d_out
    gemm_tn<float, float, float><<<dim3(4096 / 16, S_ / 16), blk16, 0, stream>>>(
        coutb, w_o, out, nullptr, S_, 4096, 4096, 0);
}

// Round 3
// 3254.893 us; speedup vs baseline: 2.2046x; 2.2046x over previous
//
#include <hip/hip_runtime.h>
#include <hip/hip_bf16.h>

typedef __hip_bfloat16 bf16;

#define NEGF (-3.402823466e38f)
#define SCALE 0.08838834764831845f  // 128^-0.5

constexpr int S_    = 1024;
constexpr int H_    = 32;
constexpr int KVH_  = 8;
constexpr int DH_   = 128;
constexpr int QKVN  = 6144;   // H*DH + 2*KVH*DH
constexpr int NC_   = 64;     // S/CB
constexpr int CD_   = 2048;   // CB*DH

// ---------------------------------------------------------------------------
// 128x128-tile fp32 GEMM:  C[M,N] = A[M,K] * B[N,K]^T  (+bias, act in direct
// mode).  256 threads = 4 waves in a 2x2 wave grid; each wave owns 64x64;
// each lane (8x8 grid within wave) computes an 8x8 register tile.
// All LDS reads/writes are <=2-way bank aliases (free on CDNA4).
// If Cpart != nullptr: split-K partial mode, blockIdx.z selects K-chunk of
// length k_len, raw partial written to Cpart + z*M*N (bias/act deferred).
// Requires M % 128 == 0, K % 16 == 0, N % 4 == 0.
// ---------------------------------------------------------------------------
__global__ __launch_bounds__(256)
void gemm128(const float* __restrict__ A, const float* __restrict__ B,
             float* __restrict__ C, float* __restrict__ Cpart,
             const float* __restrict__ bias,
             int M, int N, int K, int k_len, int act)
{
    __shared__ float As[16][132];
    __shared__ float Bs[16][132];
    const int tid  = threadIdx.x;
    const int wave = tid >> 6, lane = tid & 63;
    const int wr = wave >> 1, wc = wave & 1;
    const int ro = wr * 64 + (lane >> 3) * 8;   // row offset in tile
    const int co = wc * 64 + (lane & 7) * 8;    // col offset in tile
    const int bm = blockIdx.y * 128, bn = blockIdx.x * 128;
    const int z  = blockIdx.z;
    const int kbeg = z * k_len;
    const int lr = tid >> 2;          // 0..63 staging row
    const int kq = (tid & 3) * 4;     // staging k quad

    float acc[8][8];
    #pragma unroll
    for (int i = 0; i < 8; ++i)
        #pragma unroll
        for (int j = 0; j < 8; ++j) acc[i][j] = 0.f;

    for (int k0 = kbeg; k0 < kbeg + k_len; k0 += 16) {
        #pragma unroll
        for (int h = 0; h < 2; ++h) {
            int r = lr + h * 64;
            float4 av = make_float4(0.f, 0.f, 0.f, 0.f);
            float4 bv = make_float4(0.f, 0.f, 0.f, 0.f);
            if (bm + r < M) av = *(const float4*)&A[(size_t)(bm + r) * K + k0 + kq];
            if (bn + r < N) bv = *(const float4*)&B[(size_t)(bn + r) * K + k0 + kq];
            As[kq + 0][r] = av.x; As[kq + 1][r] = av.y;
            As[kq + 2][r] = av.z; As[kq + 3][r] = av.w;
            Bs[kq + 0][r] = bv.x; Bs[kq + 1][r] = bv.y;
            Bs[kq + 2][r] = bv.z; Bs[kq + 3][r] = bv.w;
        }
        __syncthreads();
        #pragma unroll
        for (int kk = 0; kk < 16; ++kk) {
            float4 a0 = *(const float4*)&As[kk][ro];
            float4 a1 = *(const float4*)&As[kk][ro + 4];
            float4 b0 = *(const float4*)&Bs[kk][co];
            float4 b1 = *(const float4*)&Bs[kk][co + 4];
            float a[8] = {a0.x, a0.y, a0.z, a0.w, a1.x, a1.y, a1.z, a1.w};
            float b[8] = {b0.x, b0.y, b0.z, b0.w, b1.x, b1.y, b1.z, b1.w};
            #pragma unroll
            for (int i = 0; i < 8; ++i)
                #pragma unroll
                for (int j = 0; j < 8; ++j)
                    acc[i][j] += a[i] * b[j];
        }
        __syncthreads();
    }

    if (Cpart) {
        float* P = Cpart + (size_t)z * M * N;
        #pragma unroll
        for (int i = 0; i < 8; ++i) {
            int row = bm + ro + i;
            #pragma unroll
            for (int jq = 0; jq < 2; ++jq) {
                int col = bn + co + jq * 4;
                if (col < N) {
                    float4 v = make_float4(acc[i][jq * 4 + 0], acc[i][jq * 4 + 1],
                                           acc[i][jq * 4 + 2], acc[i][jq * 4 + 3]);
                    *(float4*)&P[(size_t)row * N + col] = v;
                }
            }
        }
    } else {
        #pragma unroll
        for (int i = 0; i < 8; ++i) {
            int row = bm + ro + i;
            #pragma unroll
            for (int jq = 0; jq < 2; ++jq) {
                int col = bn + co + jq * 4;
                if (col < N) {
                    float4 v = make_float4(acc[i][jq * 4 + 0], acc[i][jq * 4 + 1],
                                           acc[i][jq * 4 + 2], acc[i][jq * 4 + 3]);
                    if (bias) {
                        float4 bv = *(const float4*)&bias[col];
                        v.x += bv.x; v.y += bv.y; v.z += bv.z; v.w += bv.w;
                    }
                    if (act == 1) {
                        v.x = fmaxf(v.x, 0.f); v.y = fmaxf(v.y, 0.f);
                        v.z = fmaxf(v.z, 0.f); v.w = fmaxf(v.w, 0.f);
                    } else if (act == 2) {
                        v.x = 1.f / (1.f + expf(-v.x)); v.y = 1.f / (1.f + expf(-v.y));
                        v.z = 1.f / (1.f + expf(-v.z)); v.w = 1.f / (1.f + expf(-v.w));
                    }
                    *(float4*)&C[(size_t)row * N + col] = v;
                }
            }
        }
    }
}

// ---------------------------------------------------------------------------
// Split-K reduce: C = act( sum_z P[z] + bias ).  float4 path, MN % 4 == 0,
// N % 4 == 0.
// ---------------------------------------------------------------------------
__global__ void reduce_slices(const float* __restrict__ P, float* __restrict__ C,
                              const float* __restrict__ bias,
                              int MN, int N, int KS, int act)
{
    int i4 = blockIdx.x * blockDim.x + threadIdx.x;
    size_t base = (size_t)i4 * 4;
    if (base >= (size_t)MN) return;
    float4 s = *(const float4*)&P[base];
    for (int z = 1; z < KS; ++z) {
        float4 v = *(const float4*)&P[(size_t)z * MN + base];
        s.x += v.x; s.y += v.y; s.z += v.z; s.w += v.w;
    }
    if (bias) {
        int col = (int)(base % N);
        float4 bv = *(const float4*)&bias[col];
        s.x += bv.x; s.y += bv.y; s.z += bv.z; s.w += bv.w;
    }
    if (act == 1) {
        s.x = fmaxf(s.x, 0.f); s.y = fmaxf(s.y, 0.f);
        s.z = fmaxf(s.z, 0.f); s.w = fmaxf(s.w, 0.f);
    } else if (act == 2) {
        s.x = 1.f / (1.f + expf(-s.x)); s.y = 1.f / (1.f + expf(-s.y));
        s.z = 1.f / (1.f + expf(-s.z)); s.w = 1.f / (1.f + expf(-s.w));
    }
    *(float4*)&C[base] = s;
}

// ---------------------------------------------------------------------------
// ck_in/cv_in: (k + k_pos), (v + v_pos) reshaped to [KVH*NC, CB*DH]
// ---------------------------------------------------------------------------
__global__ void build_cin(const float* __restrict__ qkv,
                          const float* __restrict__ k_pos,
                          const float* __restrict__ v_pos,
                          float* __restrict__ ckin, float* __restrict__ cvin)
{
    int idx = blockIdx.x * blockDim.x + threadIdx.x;       // KVH*S*DH
    if (idx >= KVH_ * S_ * DH_) return;
    int d = idx & 127;
    int s = (idx >> 7) & 1023;
    int h = idx >> 17;
    int c = s >> 4, t = s & 15;
    float kv = qkv[(size_t)s * QKVN + 4096 + h * DH_ + d];
    float vv = qkv[(size_t)s * QKVN + 5120 + h * DH_ + d];
    size_t row = (size_t)h * NC_ + c;
    size_t col = (size_t)t * DH_ + d;
    ckin[row * CD_ + col] = kv + k_pos[(h * 16 + t) * DH_ + d];
    cvin[row * CD_ + col] = vv + v_pos[(h * 16 + t) * DH_ + d];
}

// ---------------------------------------------------------------------------
// ckf/cvf [KVH, 65, DH]:  row 0 = mem_kv, rows 1..64 = compressed body
// ---------------------------------------------------------------------------
__global__ void assemble_c(const float* __restrict__ ckb, const float* __restrict__ cvb,
                           const float* __restrict__ mem_kv,
                           float* __restrict__ ckf, float* __restrict__ cvf)
{
    int idx = blockIdx.x * blockDim.x + threadIdx.x;       // KVH*65*DH
    if (idx >= KVH_ * 65 * DH_) return;
    int d = idx & 127;
    int j = (idx >> 7) % 65;
    int h = idx / (65 * DH_);
    if (j == 0) {
        ckf[idx] = mem_kv[(0 * KVH_ + h) * DH_ + d];
        cvf[idx] = mem_kv[(1 * KVH_ + h) * DH_ + d];
    } else {
        ckf[idx] = ckb[((size_t)h * NC_ + (j - 1)) * DH_ + d];
        cvf[idx] = cvb[((size_t)h * NC_ + (j - 1)) * DH_ + d];
    }
}

// ---------------------------------------------------------------------------
// Compressed attention: one block per (kvh, g, s).  65 keys (mem + 64 blocks).
// Stores masked scores to csim (needed for importance) and c_out [s,h,d].
// ---------------------------------------------------------------------------
__global__ void compress_attn(const float* __restrict__ qkv,
                              const float* __restrict__ ckf,
                              const float* __restrict__ cvf,
                              float* __restrict__ csim, float* __restrict__ cout)
{
    int b = blockIdx.x;
    int s = b & 1023;
    int g = (b >> 10) & 3;
    int h = b >> 12;               // kvh
    int qh = h * 4 + g;
    int tid = threadIdx.x;         // 128 threads
    __shared__ float qrow[128];
    __shared__ float sim[65];
    __shared__ float p[65];
    __shared__ float inv_den;
    qrow[tid] = qkv[(size_t)s * QKVN + qh * DH_ + tid];
    __syncthreads();
    if (tid < 65) {
        const float* krow = ckf + ((size_t)h * 65 + tid) * DH_;
        bool vis = (tid == 0) || (16 * tid - 1 < s);
        float acc = NEGF;
        if (vis) {
            acc = 0.f;
            for (int d = 0; d < 128; ++d) acc += qrow[d] * krow[d];
            acc *= SCALE;
        }
        sim[tid] = acc;
        csim[(((size_t)h * 4 + g) * S_ + s) * 65 + tid] = acc;
    }
    __syncthreads();
    if (tid == 0) {
        float m = sim[0];
        for (int j = 1; j < 65; ++j) m = fmaxf(m, sim[j]);
        float den = 0.f;
        for (int j = 0; j < 65; ++j) { float e = expf(sim[j] - m); p[j] = e; den += e; }
        inv_den = 1.f / den;
    }
    __syncthreads();
    float acc = 0.f;
    for (int j = 0; j < 65; ++j)
        acc += p[j] * cvf[((size_t)h * 65 + j) * DH_ + tid];
    cout[(size_t)s * 4096 + qh * DH_ + tid] = acc * inv_den;
}

// ---------------------------------------------------------------------------
// Importance softmax (with -1e3 sentinel) + top-4 (lax.top_k tie semantics:
// stable, lowest index wins on ties) + append own block.
// One block per (kvh, s), 64 threads (one wave).
// ---------------------------------------------------------------------------
__global__ void importance_topk(const float* __restrict__ csim,
                                int* __restrict__ selidx, int* __restrict__ fsel)
{
    int b = blockIdx.x;
    int s = b & 1023;
    int h = b >> 10;
    int j = threadIdx.x;            // 0..63 -> compressed block j (csim col j+1)
    float v = 0.f;
    for (int g = 0; g < 4; ++g)
        v += csim[(((size_t)h * 4 + g) * S_ + s) * 65 + 1 + j];
    v *= 0.25f;                      // mean over grouped heads (NEG -> -inf, same as jnp)
    float m = v;
    #pragma unroll
    for (int off = 32; off; off >>= 1) m = fmaxf(m, __shfl_xor(m, off));
    m = fmaxf(m, -1e3f);             // sentinel participates in the max
    float e = expf(v - m);
    float den = e;
    #pragma unroll
    for (int off = 32; off; off >>= 1) den += __shfl_xor(den, off);
    den += expf(-1e3f - m);          // sentinel term
    float pv = e / den;
    __shared__ float ps[64];
    ps[j] = pv;
    __syncthreads();
    if (j == 0) {
        size_t base5 = ((size_t)h * S_ + s) * 5;
        size_t base4 = ((size_t)h * S_ + s) * 4;
        for (int t = 0; t < 4; ++t) {
            int bi = 0; float bv = ps[0];
            for (int i = 1; i < 64; ++i)
                if (ps[i] > bv) { bv = ps[i]; bi = i; }   // strict > : lowest idx on tie
            selidx[base5 + t] = bi;
            fsel[base4 + t]   = (bv > 1e-10f) ? 1 : 0;
            ps[bi] = -1.f;
        }
        selidx[base5 + 4] = s >> 4;   // own block
    }
}

// ---------------------------------------------------------------------------
// Interleaved RoPE (theta=10000) applied in place to the q and k slices of qkv.
// ---------------------------------------------------------------------------
__global__ void rope_inplace(float* __restrict__ qkv)
{
    int idx = blockIdx.x * blockDim.x + threadIdx.x;
    const int totq = S_ * H_ * 64;             // q pairs
    const int totk = S_ * KVH_ * 64;           // k pairs
    float* base;
    int p, s;
    if (idx < totq) {
        p = idx & 63; int head = (idx >> 6) & 31; s = idx >> 11;
        base = qkv + (size_t)s * QKVN + head * DH_;
    } else {
        int i2 = idx - totq;
        if (i2 >= totk) return;
        p = i2 & 63; int head = (i2 >> 6) & 7; s = i2 >> 9;
        base = qkv + (size_t)s * QKVN + 4096 + head * DH_;
    }
    float inv = 1.f / powf(10000.f, (float)(2 * p) / 128.f);
    float ang = (float)s * inv;
    float c = cosf(ang), sn = sinf(ang);
    float x0 = base[2 * p], x1 = base[2 * p + 1];
    base[2 * p]     = x0 * c - x1 * sn;
    base[2 * p + 1] = x1 * c + x0 * sn;
}

// ---------------------------------------------------------------------------
// Fine attention: one block per (kvh, g, s).  5 blocks x 16 keys = 80 keys.
// ---------------------------------------------------------------------------
__global__ void fine_attn(const float* __restrict__ qkv,
                          const int* __restrict__ selidx, const int* __restrict__ fsel,
                          float* __restrict__ fout)
{
    int b = blockIdx.x;
    int s = b & 1023;
    int g = (b >> 10) & 3;
    int h = b >> 12;
    int qh = h * 4 + g;
    int tid = threadIdx.x;   // 128
    __shared__ float qrow[128];
    __shared__ float sim[80];
    __shared__ float p[80];
    __shared__ int   blk[5];
    __shared__ int   bvis[5];
    __shared__ float inv_den;
    if (tid < 5) {
        blk[tid]  = selidx[((size_t)h * S_ + s) * 5 + tid];
        bvis[tid] = (tid < 4) ? fsel[((size_t)h * S_ + s) * 4 + tid] : 1;
    }
    qrow[tid] = qkv[(size_t)s * QKVN + qh * DH_ + tid];
    __syncthreads();
    if (tid < 80) {
        int bi = tid >> 4, t = tid & 15;
        int pos = blk[bi] * 16 + t;
        bool vis = (bi < 4) ? (bvis[bi] != 0) : (t <= (s & 15));
        float acc = NEGF;
        if (vis) {
            const float* krow = qkv + (size_t)pos * QKVN + 4096 + h * DH_;
            acc = 0.f;
            for (int d = 0; d < 128; ++d) acc += qrow[d] * krow[d];
            acc *= SCALE;
        }
        sim[tid] = acc;
    }
    __syncthreads();
    if (tid == 0) {
        float m = sim[0];
        for (int j = 1; j < 80; ++j) m = fmaxf(m, sim[j]);
        float den = 0.f;
        for (int j = 0; j < 80; ++j) { float e = expf(sim[j] - m); p[j] = e; den += e; }
        inv_den = 1.f / den;
    }
    __syncthreads();
    float acc = 0.f;
    for (int j = 0; j < 80; ++j) {
        int pos = blk[j >> 4] * 16 + (j & 15);
        acc += p[j] * qkv[(size_t)pos * QKVN + 5120 + h * DH_ + tid];
    }
    fout[(size_t)s * 4096 + qh * DH_ + tid] = acc * inv_den;
}

// ---------------------------------------------------------------------------
// Sliding window: equivalent to causal window 0 <= s-j <= 64, j >= 0.
// ---------------------------------------------------------------------------
__global__ void sliding_attn(const float* __restrict__ qkv, float* __restrict__ sout)
{
    int b = blockIdx.x;
    int s = b & 1023;
    int qh = b >> 10;
    int kvh = qh >> 2;
    int tid = threadIdx.x;   // 128
    __shared__ float qrow[128];
    __shared__ float sim[65];
    __shared__ float p[65];
    __shared__ float inv_den;
    qrow[tid] = qkv[(size_t)s * QKVN + qh * DH_ + tid];
    __syncthreads();
    if (tid < 65) {
        int pos = s - tid;
        float acc = NEGF;
        if (pos >= 0) {
            const float* krow = qkv + (size_t)pos * QKVN + 4096 + kvh * DH_;
            acc = 0.f;
            for (int d = 0; d < 128; ++d) acc += qrow[d] * krow[d];
            acc *= SCALE;
        }
        sim[tid] = acc;
    }
    __syncthreads();
    if (tid == 0) {
        float m = sim[0];
        for (int j = 1; j < 65; ++j) m = fmaxf(m, sim[j]);
        float den = 0.f;
        for (int j = 0; j < 65; ++j) { float e = expf(sim[j] - m); p[j] = e; den += e; }
        inv_den = 1.f / den;
    }
    __syncthreads();
    float acc = 0.f;
    int lim = (s + 1 < 65) ? (s + 1) : 65;
    for (int j = 0; j < lim; ++j)
        acc += p[j] * qkv[(size_t)(s - j) * QKVN + 5120 + kvh * DH_ + tid];
    sout[(size_t)s * 4096 + qh * DH_ + tid] = acc * inv_den;
}

// ---------------------------------------------------------------------------
// gated combine: cout <- g0*cout + g1*fout + g2*sout   (layout [s, h*128+d])
// ---------------------------------------------------------------------------
__global__ void combine_gate(float* __restrict__ cout, const float* __restrict__ fout,
                             const float* __restrict__ sout, const float* __restrict__ gates)
{
    int idx = blockIdx.x * blockDim.x + threadIdx.x;   // S*4096
    if (idx >= S_ * 4096) return;
    int h = (idx >> 7) & 31;
    int s = idx >> 12;
    float g0 = gates[(size_t)s * 96 + h * 3 + 0];
    float g1 = gates[(size_t)s * 96 + h * 3 + 1];
    float g2 = gates[(size_t)s * 96 + h * 3 + 2];
    cout[idx] = g0 * cout[idx] + g1 * fout[idx] + g2 * sout[idx];
}

// ---------------------------------------------------------------------------
extern "C" void kernel_launch(void* const* d_in, const int* in_sizes, int n_in,
                              void* d_out, int out_size, void* d_ws, size_t ws_size,
                              hipStream_t stream)
{
    const float* hidden = (const float*)d_in[0];
    const float* w_qkv  = (const float*)d_in[1];
    const float* w_o    = (const float*)d_in[2];
    const float* k_pos  = (const float*)d_in[3];
    const float* v_pos  = (const float*)d_in[4];
    const float* k_w1   = (const float*)d_in[5];
    const float* k_b1   = (const float*)d_in[6];
    const float* k_w2   = (const float*)d_in[7];
    const float* k_b2   = (const float*)d_in[8];
    const float* v_w1   = (const float*)d_in[9];
    const float* v_b1   = (const float*)d_in[10];
    const float* v_w2   = (const float*)d_in[11];
    const float* v_b2   = (const float*)d_in[12];
    const float* mem_kv = (const float*)d_in[13];
    const float* w_gate = (const float*)d_in[14];
    const float* b_gate = (const float*)d_in[15];
    float* out = (float*)d_out;

    float* ws = (float*)d_ws;
    size_t o = 0;
    float* qkv    = ws + o; o += (size_t)S_ * QKVN;
    float* ckin   = ws + o; o += (size_t)512 * CD_;
    float* cvin   = ws + o; o += (size_t)512 * CD_;
    float* h1     = ws + o; o += (size_t)512 * CD_;
    float* ckb    = ws + o; o += (size_t)512 * DH_;
    float* cvb    = ws + o; o += (size_t)512 * DH_;
    float* ckf    = ws + o; o += (size_t)KVH_ * 65 * DH_;
    float* cvf    = ws + o; o += (size_t)KVH_ * 65 * DH_;
    float* csim   = ws + o; o += (size_t)KVH_ * 4 * S_ * 65;
    float* coutb  = ws + o; o += (size_t)S_ * 4096;
    float* foutb  = ws + o; o += (size_t)S_ * 4096;
    float* soutb  = ws + o; o += (size_t)S_ * 4096;
    float* gatesb = ws + o; o += (size_t)S_ * 96;
    int*   selidx = (int*)(ws + o); o += (size_t)KVH_ * S_ * 5;
    int*   fsel   = (int*)(ws + o); o += (size_t)KVH_ * S_ * 4;

    // split-K partial buffer: aliased onto foutb (4,194,304 floats) — foutb is
    // only written at step 12, long after the last split-K reduce completes.
    float* P = foutb;

    // 1. qkv projection: [1024,6144] (direct mode)
    gemm128<<<dim3(QKVN / 128, S_ / 128, 1), 256, 0, stream>>>(
        hidden, w_qkv, qkv, nullptr, nullptr, S_, QKVN, 4096, 4096, 0);

    // 2. gates [1024,96]: split-K=16 (N too small to fill the grid otherwise)
    gemm128<<<dim3(1, S_ / 128, 16), 256, 0, stream>>>(
        hidden, w_gate, nullptr, P, nullptr, S_, 96, 4096, 256, 0);
    reduce_slices<<<(S_ * 96 / 4 + 255) / 256, 256, 0, stream>>>(
        P, gatesb, b_gate, S_ * 96, 96, 16, 2);

    // 3. compress inputs
    build_cin<<<(KVH_ * S_ * DH_ + 255) / 256, 256, 0, stream>>>(qkv, k_pos, v_pos, ckin, cvin);

    // 4-7. compress MLPs via split-K (K path then V path)
    gemm128<<<dim3(CD_ / 128, 4, 4), 256, 0, stream>>>(
        ckin, k_w1, nullptr, P, nullptr, 512, CD_, CD_, 512, 0);
    reduce_slices<<<(512 * CD_ / 4 + 255) / 256, 256, 0, stream>>>(
        P, h1, k_b1, 512 * CD_, CD_, 4, 1);
    gemm128<<<dim3(1, 4, 16), 256, 0, stream>>>(
        h1, k_w2, nullptr, P, nullptr, 512, DH_, CD_, 128, 0);
    reduce_slices<<<(512 * DH_ / 4 + 255) / 256, 256, 0, stream>>>(
        P, ckb, k_b2, 512 * DH_, DH_, 16, 0);

    gemm128<<<dim3(CD_ / 128, 4, 4), 256, 0, stream>>>(
        cvin, v_w1, nullptr, P, nullptr, 512, CD_, CD_, 512, 0);
    reduce_slices<<<(512 * CD_ / 4 + 255) / 256, 256, 0, stream>>>(
        P, h1, v_b1, 512 * CD_, CD_, 4, 1);
    gemm128<<<dim3(1, 4, 16), 256, 0, stream>>>(
        h1, v_w2, nullptr, P, nullptr, 512, DH_, CD_, 128, 0);
    reduce_slices<<<(512 * DH_ / 4 + 255) / 256, 256, 0, stream>>>(
        P, cvb, v_b2, 512 * DH_, DH_, 16, 0);

    // 8. prepend mem token
    assemble_c<<<(KVH_ * 65 * DH_ + 255) / 256, 256, 0, stream>>>(ckb, cvb, mem_kv, ckf, cvf);

    // 9. compressed attention (also writes masked csim for importance)
    compress_attn<<<KVH_ * 4 * S_, 128, 0, stream>>>(qkv, ckf, cvf, csim, coutb);

    // 10. importance + top-k selection
    importance_topk<<<KVH_ * S_, 64, 0, stream>>>(csim, selidx, fsel);

    // 11. RoPE in place on q and k slices of qkv
    {
        int tot = S_ * H_ * 64 + S_ * KVH_ * 64;
        rope_inplace<<<(tot + 255) / 256, 256, 0, stream>>>(qkv);
    }

    // 12. fine (selected-block) attention
    fine_attn<<<KVH_ * 4 * S_, 128, 0, stream>>>(qkv, selidx, fsel, foutb);

    // 13. sliding-window attention
    sliding_attn<<<H_ * S_, 128, 0, stream>>>(qkv, soutb);

    // 14. gated combine into coutb
    combine_gate<<<(S_ * 4096 + 255) / 256, 256, 0, stream>>>(coutb, foutb, soutb, gatesb);

    // 15. output projection -> d_out (direct mode)
    gemm128<<<dim3(4096 / 128, S_ / 128, 1), 256, 0, stream>>>(
        coutb, w_o, out, nullptr, nullptr, S_, 4096, 4096, 4096, 0);
}

// Round 4
// 1650.775 us; speedup vs baseline: 4.3469x; 1.9717x over previous
//
#include <hip/hip_runtime.h>
#include <hip/hip_bf16.h>

typedef __hip_bfloat16 bf16;
typedef __attribute__((ext_vector_type(8))) short short8;   // 8 bf16 = 4 VGPRs
typedef __attribute__((ext_vector_type(4))) float f32x4;

#define NEGF (-3.402823466e38f)
#define SCALE 0.08838834764831845f  // 128^-0.5

constexpr int S_    = 1024;
constexpr int H_    = 32;
constexpr int KVH_  = 8;
constexpr int DH_   = 128;
constexpr int QKVN  = 6144;   // H*DH + 2*KVH*DH
constexpr int NC_   = 64;     // S/CB
constexpr int CD_   = 2048;   // CB*DH

__device__ __forceinline__ short f2bf(float x) {
    union { float f; unsigned u; } v; v.f = x;
    unsigned r = v.u + 0x7fffu + ((v.u >> 16) & 1u);   // round-to-nearest-even
    return (short)(r >> 16);
}
__device__ __forceinline__ float bf2f(short h) {
    union { float f; unsigned u; } v; v.u = ((unsigned)(unsigned short)h) << 16;
    return v.f;
}

// ---------------------------------------------------------------------------
// MFMA bf16x3 GEMM: C[M,N] = A[M,K] * B[N,K]^T in ~fp32 precision.
// A,B fp32 in global; staged per 128x128x32 tile into LDS as (hi,lo) bf16.
// 256 thr = 4 waves (2x2), each wave 64x64 = 4x4 MFMA tiles of 16x16x32.
// Per tile: acc += Ah*Bh + Ah*Bl + Al*Bh  (AlBl ~2^-16 rel, dropped).
// Cpart!=nullptr: split-K partial mode (blockIdx.z, chunk k_len).
// Requires M,N % 128 == 0, K % 32 == 0.
// ---------------------------------------------------------------------------
__global__ __launch_bounds__(256)
void gemm_mfma(const float* __restrict__ A, const float* __restrict__ B,
               float* __restrict__ C, float* __restrict__ Cpart,
               const float* __restrict__ bias,
               int M, int N, int K, int k_len, int act)
{
    // LDS cell (kq, m) holds 8 bf16 (16 B): k = kq*8..+8 of row m
    __shared__ short Ah[4 * 128 * 8];
    __shared__ short Al[4 * 128 * 8];
    __shared__ short Bh[4 * 128 * 8];
    __shared__ short Bl[4 * 128 * 8];
    const int tid  = threadIdx.x;
    const int lane = tid & 63, wave = tid >> 6;
    const int wr = wave >> 1, wc = wave & 1;
    const int qd = lane >> 4, l16 = lane & 15;
    const int bm = blockIdx.y * 128, bn = blockIdx.x * 128;
    const int kbeg = blockIdx.z * k_len;
    const int skq = tid & 3;          // staging k-quad (0..3)
    const int sm  = tid >> 2;         // staging row (0..63, +64)

    f32x4 zero = {0.f, 0.f, 0.f, 0.f};
    f32x4 acc[4][4];
    #pragma unroll
    for (int i = 0; i < 4; ++i)
        #pragma unroll
        for (int j = 0; j < 4; ++j) acc[i][j] = zero;

    for (int k0 = kbeg; k0 < kbeg + k_len; k0 += 32) {
        #pragma unroll
        for (int half = 0; half < 2; ++half) {
            int m = sm + half * 64;
            const float* pa = &A[(size_t)(bm + m) * K + k0 + skq * 8];
            const float* pb = &B[(size_t)(bn + m) * K + k0 + skq * 8];
            float4 a0 = *(const float4*)pa;
            float4 a1 = *(const float4*)(pa + 4);
            float4 b0 = *(const float4*)pb;
            float4 b1 = *(const float4*)(pb + 4);
            int cell = (skq * 128 + m) * 8;
            float ea[8] = {a0.x, a0.y, a0.z, a0.w, a1.x, a1.y, a1.z, a1.w};
            float eb[8] = {b0.x, b0.y, b0.z, b0.w, b1.x, b1.y, b1.z, b1.w};
            short8 ha, la, hb, lb;
            #pragma unroll
            for (int j = 0; j < 8; ++j) {
                short h = f2bf(ea[j]); ha[j] = h; la[j] = f2bf(ea[j] - bf2f(h));
                short g = f2bf(eb[j]); hb[j] = g; lb[j] = f2bf(eb[j] - bf2f(g));
            }
            *(short8*)&Ah[cell] = ha; *(short8*)&Al[cell] = la;
            *(short8*)&Bh[cell] = hb; *(short8*)&Bl[cell] = lb;
        }
        __syncthreads();
        short8 fah[4], fal[4], fbh[4], fbl[4];
        #pragma unroll
        for (int t = 0; t < 4; ++t) {
            int ca = (qd * 128 + wr * 64 + t * 16 + l16) * 8;
            int cb = (qd * 128 + wc * 64 + t * 16 + l16) * 8;
            fah[t] = *(const short8*)&Ah[ca]; fal[t] = *(const short8*)&Al[ca];
            fbh[t] = *(const short8*)&Bh[cb]; fbl[t] = *(const short8*)&Bl[cb];
        }
        #pragma unroll
        for (int i = 0; i < 4; ++i)
            #pragma unroll
            for (int j = 0; j < 4; ++j) {
                acc[i][j] = __builtin_amdgcn_mfma_f32_16x16x32_bf16(fah[i], fbh[j], acc[i][j], 0, 0, 0);
                acc[i][j] = __builtin_amdgcn_mfma_f32_16x16x32_bf16(fah[i], fbl[j], acc[i][j], 0, 0, 0);
                acc[i][j] = __builtin_amdgcn_mfma_f32_16x16x32_bf16(fal[i], fbh[j], acc[i][j], 0, 0, 0);
            }
        __syncthreads();
    }

    // epilogue: C/D layout col=lane&15, row=qd*4+reg (m89-verified)
    float* dst = Cpart ? (Cpart + (size_t)blockIdx.z * M * N) : C;
    #pragma unroll
    for (int i = 0; i < 4; ++i) {
        #pragma unroll
        for (int j = 0; j < 4; ++j) {
            int row0 = bm + wr * 64 + i * 16 + qd * 4;
            int col  = bn + wc * 64 + j * 16 + l16;
            #pragma unroll
            for (int r = 0; r < 4; ++r) {
                float v = acc[i][j][r];
                if (!Cpart) {
                    if (bias) v += bias[col];
                    if (act == 1) v = fmaxf(v, 0.f);
                    else if (act == 2) v = 1.f / (1.f + expf(-v));
                }
                dst[(size_t)(row0 + r) * N + col] = v;
            }
        }
    }
}

// ---------------------------------------------------------------------------
// Vector fallback GEMM (small N / split-K): 128x128 tile, 8x8 regs per lane.
// ---------------------------------------------------------------------------
__global__ __launch_bounds__(256)
void gemm128(const float* __restrict__ A, const float* __restrict__ B,
             float* __restrict__ C, float* __restrict__ Cpart,
             const float* __restrict__ bias,
             int M, int N, int K, int k_len, int act)
{
    __shared__ float As[16][132];
    __shared__ float Bs[16][132];
    const int tid  = threadIdx.x;
    const int wave = tid >> 6, lane = tid & 63;
    const int wr = wave >> 1, wc = wave & 1;
    const int ro = wr * 64 + (lane >> 3) * 8;
    const int co = wc * 64 + (lane & 7) * 8;
    const int bm = blockIdx.y * 128, bn = blockIdx.x * 128;
    const int z  = blockIdx.z;
    const int kbeg = z * k_len;
    const int lr = tid >> 2;
    const int kq = (tid & 3) * 4;

    float acc[8][8];
    #pragma unroll
    for (int i = 0; i < 8; ++i)
        #pragma unroll
        for (int j = 0; j < 8; ++j) acc[i][j] = 0.f;

    for (int k0 = kbeg; k0 < kbeg + k_len; k0 += 16) {
        #pragma unroll
        for (int h = 0; h < 2; ++h) {
            int r = lr + h * 64;
            float4 av = make_float4(0.f, 0.f, 0.f, 0.f);
            float4 bv = make_float4(0.f, 0.f, 0.f, 0.f);
            if (bm + r < M) av = *(const float4*)&A[(size_t)(bm + r) * K + k0 + kq];
            if (bn + r < N) bv = *(const float4*)&B[(size_t)(bn + r) * K + k0 + kq];
            As[kq + 0][r] = av.x; As[kq + 1][r] = av.y;
            As[kq + 2][r] = av.z; As[kq + 3][r] = av.w;
            Bs[kq + 0][r] = bv.x; Bs[kq + 1][r] = bv.y;
            Bs[kq + 2][r] = bv.z; Bs[kq + 3][r] = bv.w;
        }
        __syncthreads();
        #pragma unroll
        for (int kk = 0; kk < 16; ++kk) {
            float4 a0 = *(const float4*)&As[kk][ro];
            float4 a1 = *(const float4*)&As[kk][ro + 4];
            float4 b0 = *(const float4*)&Bs[kk][co];
            float4 b1 = *(const float4*)&Bs[kk][co + 4];
            float a[8] = {a0.x, a0.y, a0.z, a0.w, a1.x, a1.y, a1.z, a1.w};
            float b[8] = {b0.x, b0.y, b0.z, b0.w, b1.x, b1.y, b1.z, b1.w};
            #pragma unroll
            for (int i = 0; i < 8; ++i)
                #pragma unroll
                for (int j = 0; j < 8; ++j)
                    acc[i][j] += a[i] * b[j];
        }
        __syncthreads();
    }

    if (Cpart) {
        float* P = Cpart + (size_t)z * M * N;
        #pragma unroll
        for (int i = 0; i < 8; ++i) {
            int row = bm + ro + i;
            #pragma unroll
            for (int jq = 0; jq < 2; ++jq) {
                int col = bn + co + jq * 4;
                if (col < N) {
                    float4 v = make_float4(acc[i][jq * 4 + 0], acc[i][jq * 4 + 1],
                                           acc[i][jq * 4 + 2], acc[i][jq * 4 + 3]);
                    *(float4*)&P[(size_t)row * N + col] = v;
                }
            }
        }
    } else {
        #pragma unroll
        for (int i = 0; i < 8; ++i) {
            int row = bm + ro + i;
            #pragma unroll
            for (int jq = 0; jq < 2; ++jq) {
                int col = bn + co + jq * 4;
                if (col < N) {
                    float4 v = make_float4(acc[i][jq * 4 + 0], acc[i][jq * 4 + 1],
                                           acc[i][jq * 4 + 2], acc[i][jq * 4 + 3]);
                    if (bias) {
                        float4 bv = *(const float4*)&bias[col];
                        v.x += bv.x; v.y += bv.y; v.z += bv.z; v.w += bv.w;
                    }
                    if (act == 1) {
                        v.x = fmaxf(v.x, 0.f); v.y = fmaxf(v.y, 0.f);
                        v.z = fmaxf(v.z, 0.f); v.w = fmaxf(v.w, 0.f);
                    } else if (act == 2) {
                        v.x = 1.f / (1.f + expf(-v.x)); v.y = 1.f / (1.f + expf(-v.y));
                        v.z = 1.f / (1.f + expf(-v.z)); v.w = 1.f / (1.f + expf(-v.w));
                    }
                    *(float4*)&C[(size_t)row * N + col] = v;
                }
            }
        }
    }
}

// ---------------------------------------------------------------------------
// Split-K reduce: C = act( sum_z P[z] + bias )
// ---------------------------------------------------------------------------
__global__ void reduce_slices(const float* __restrict__ P, float* __restrict__ C,
                              const float* __restrict__ bias,
                              int MN, int N, int KS, int act)
{
    int i4 = blockIdx.x * blockDim.x + threadIdx.x;
    size_t base = (size_t)i4 * 4;
    if (base >= (size_t)MN) return;
    float4 s = *(const float4*)&P[base];
    for (int z = 1; z < KS; ++z) {
        float4 v = *(const float4*)&P[(size_t)z * MN + base];
        s.x += v.x; s.y += v.y; s.z += v.z; s.w += v.w;
    }
    if (bias) {
        int col = (int)(base % N);
        float4 bv = *(const float4*)&bias[col];
        s.x += bv.x; s.y += bv.y; s.z += bv.z; s.w += bv.w;
    }
    if (act == 1) {
        s.x = fmaxf(s.x, 0.f); s.y = fmaxf(s.y, 0.f);
        s.z = fmaxf(s.z, 0.f); s.w = fmaxf(s.w, 0.f);
    } else if (act == 2) {
        s.x = 1.f / (1.f + expf(-s.x)); s.y = 1.f / (1.f + expf(-s.y));
        s.z = 1.f / (1.f + expf(-s.z)); s.w = 1.f / (1.f + expf(-s.w));
    }
    *(float4*)&C[base] = s;
}

// ---------------------------------------------------------------------------
__global__ void build_cin(const float* __restrict__ qkv,
                          const float* __restrict__ k_pos,
                          const float* __restrict__ v_pos,
                          float* __restrict__ ckin, float* __restrict__ cvin)
{
    int idx = blockIdx.x * blockDim.x + threadIdx.x;       // KVH*S*DH
    if (idx >= KVH_ * S_ * DH_) return;
    int d = idx & 127;
    int s = (idx >> 7) & 1023;
    int h = idx >> 17;
    int c = s >> 4, t = s & 15;
    float kv = qkv[(size_t)s * QKVN + 4096 + h * DH_ + d];
    float vv = qkv[(size_t)s * QKVN + 5120 + h * DH_ + d];
    size_t row = (size_t)h * NC_ + c;
    size_t col = (size_t)t * DH_ + d;
    ckin[row * CD_ + col] = kv + k_pos[(h * 16 + t) * DH_ + d];
    cvin[row * CD_ + col] = vv + v_pos[(h * 16 + t) * DH_ + d];
}

// ---------------------------------------------------------------------------
__global__ void assemble_c(const float* __restrict__ ckb, const float* __restrict__ cvb,
                           const float* __restrict__ mem_kv,
                           float* __restrict__ ckf, float* __restrict__ cvf)
{
    int idx = blockIdx.x * blockDim.x + threadIdx.x;       // KVH*65*DH
    if (idx >= KVH_ * 65 * DH_) return;
    int d = idx & 127;
    int j = (idx >> 7) % 65;
    int h = idx / (65 * DH_);
    if (j == 0) {
        ckf[idx] = mem_kv[(0 * KVH_ + h) * DH_ + d];
        cvf[idx] = mem_kv[(1 * KVH_ + h) * DH_ + d];
    } else {
        ckf[idx] = ckb[((size_t)h * NC_ + (j - 1)) * DH_ + d];
        cvf[idx] = cvb[((size_t)h * NC_ + (j - 1)) * DH_ + d];
    }
}

// ---------------------------------------------------------------------------
__global__ void compress_attn(const float* __restrict__ qkv,
                              const float* __restrict__ ckf,
                              const float* __restrict__ cvf,
                              float* __restrict__ csim, float* __restrict__ cout)
{
    int b = blockIdx.x;
    int s = b & 1023;
    int g = (b >> 10) & 3;
    int h = b >> 12;               // kvh
    int qh = h * 4 + g;
    int tid = threadIdx.x;         // 128 threads
    __shared__ float qrow[128];
    __shared__ float sim[65];
    __shared__ float p[65];
    __shared__ float inv_den;
    qrow[tid] = qkv[(size_t)s * QKVN + qh * DH_ + tid];
    __syncthreads();
    if (tid < 65) {
        const float* krow = ckf + ((size_t)h * 65 + tid) * DH_;
        bool vis = (tid == 0) || (16 * tid - 1 < s);
        float acc = NEGF;
        if (vis) {
            acc = 0.f;
            for (int d = 0; d < 128; ++d) acc += qrow[d] * krow[d];
            acc *= SCALE;
        }
        sim[tid] = acc;
        csim[(((size_t)h * 4 + g) * S_ + s) * 65 + tid] = acc;
    }
    __syncthreads();
    if (tid == 0) {
        float m = sim[0];
        for (int j = 1; j < 65; ++j) m = fmaxf(m, sim[j]);
        float den = 0.f;
        for (int j = 0; j < 65; ++j) { float e = expf(sim[j] - m); p[j] = e; den += e; }
        inv_den = 1.f / den;
    }
    __syncthreads();
    float acc = 0.f;
    for (int j = 0; j < 65; ++j)
        acc += p[j] * cvf[((size_t)h * 65 + j) * DH_ + tid];
    cout[(size_t)s * 4096 + qh * DH_ + tid] = acc * inv_den;
}

// ---------------------------------------------------------------------------
__global__ void importance_topk(const float* __restrict__ csim,
                                int* __restrict__ selidx, int* __restrict__ fsel)
{
    int b = blockIdx.x;
    int s = b & 1023;
    int h = b >> 10;
    int j = threadIdx.x;            // 0..63
    float v = 0.f;
    for (int g = 0; g < 4; ++g)
        v += csim[(((size_t)h * 4 + g) * S_ + s) * 65 + 1 + j];
    v *= 0.25f;
    float m = v;
    #pragma unroll
    for (int off = 32; off; off >>= 1) m = fmaxf(m, __shfl_xor(m, off));
    m = fmaxf(m, -1e3f);
    float e = expf(v - m);
    float den = e;
    #pragma unroll
    for (int off = 32; off; off >>= 1) den += __shfl_xor(den, off);
    den += expf(-1e3f - m);
    float pv = e / den;
    __shared__ float ps[64];
    ps[j] = pv;
    __syncthreads();
    if (j == 0) {
        size_t base5 = ((size_t)h * S_ + s) * 5;
        size_t base4 = ((size_t)h * S_ + s) * 4;
        for (int t = 0; t < 4; ++t) {
            int bi = 0; float bv = ps[0];
            for (int i = 1; i < 64; ++i)
                if (ps[i] > bv) { bv = ps[i]; bi = i; }
            selidx[base5 + t] = bi;
            fsel[base4 + t]   = (bv > 1e-10f) ? 1 : 0;
            ps[bi] = -1.f;
        }
        selidx[base5 + 4] = s >> 4;
    }
}

// ---------------------------------------------------------------------------
__global__ void rope_inplace(float* __restrict__ qkv)
{
    int idx = blockIdx.x * blockDim.x + threadIdx.x;
    const int totq = S_ * H_ * 64;
    const int totk = S_ * KVH_ * 64;
    float* base;
    int p, s;
    if (idx < totq) {
        p = idx & 63; int head = (idx >> 6) & 31; s = idx >> 11;
        base = qkv + (size_t)s * QKVN + head * DH_;
    } else {
        int i2 = idx - totq;
        if (i2 >= totk) return;
        p = i2 & 63; int head = (i2 >> 6) & 7; s = i2 >> 9;
        base = qkv + (size_t)s * QKVN + 4096 + head * DH_;
    }
    float inv = 1.f / powf(10000.f, (float)(2 * p) / 128.f);
    float ang = (float)s * inv;
    float c = cosf(ang), sn = sinf(ang);
    float x0 = base[2 * p], x1 = base[2 * p + 1];
    base[2 * p]     = x0 * c - x1 * sn;
    base[2 * p + 1] = x1 * c + x0 * sn;
}

// ---------------------------------------------------------------------------
__global__ void fine_attn(const float* __restrict__ qkv,
                          const int* __restrict__ selidx, const int* __restrict__ fsel,
                          float* __restrict__ fout)
{
    int b = blockIdx.x;
    int s = b & 1023;
    int g = (b >> 10) & 3;
    int h = b >> 12;
    int qh = h * 4 + g;
    int tid = threadIdx.x;   // 128
    __shared__ float qrow[128];
    __shared__ float sim[80];
    __shared__ float p[80];
    __shared__ int   blk[5];
    __shared__ int   bvis[5];
    __shared__ float inv_den;
    if (tid < 5) {
        blk[tid]  = selidx[((size_t)h * S_ + s) * 5 + tid];
        bvis[tid] = (tid < 4) ? fsel[((size_t)h * S_ + s) * 4 + tid] : 1;
    }
    qrow[tid] = qkv[(size_t)s * QKVN + qh * DH_ + tid];
    __syncthreads();
    if (tid < 80) {
        int bi = tid >> 4, t = tid & 15;
        int pos = blk[bi] * 16 + t;
        bool vis = (bi < 4) ? (bvis[bi] != 0) : (t <= (s & 15));
        float acc = NEGF;
        if (vis) {
            const float* krow = qkv + (size_t)pos * QKVN + 4096 + h * DH_;
            acc = 0.f;
            for (int d = 0; d < 128; ++d) acc += qrow[d] * krow[d];
            acc *= SCALE;
        }
        sim[tid] = acc;
    }
    __syncthreads();
    if (tid == 0) {
        float m = sim[0];
        for (int j = 1; j < 80; ++j) m = fmaxf(m, sim[j]);
        float den = 0.f;
        for (int j = 0; j < 80; ++j) { float e = expf(sim[j] - m); p[j] = e; den += e; }
        inv_den = 1.f / den;
    }
    __syncthreads();
    float acc = 0.f;
    for (int j = 0; j < 80; ++j) {
        int pos = blk[j >> 4] * 16 + (j & 15);
        acc += p[j] * qkv[(size_t)pos * QKVN + 5120 + h * DH_ + tid];
    }
    fout[(size_t)s * 4096 + qh * DH_ + tid] = acc * inv_den;
}

// ---------------------------------------------------------------------------
__global__ void sliding_attn(const float* __restrict__ qkv, float* __restrict__ sout)
{
    int b = blockIdx.x;
    int s = b & 1023;
    int qh = b >> 10;
    int kvh = qh >> 2;
    int tid = threadIdx.x;   // 128
    __shared__ float qrow[128];
    __shared__ float sim[65];
    __shared__ float p[65];
    __shared__ float inv_den;
    qrow[tid] = qkv[(size_t)s * QKVN + qh * DH_ + tid];
    __syncthreads();
    if (tid < 65) {
        int pos = s - tid;
        float acc = NEGF;
        if (pos >= 0) {
            const float* krow = qkv + (size_t)pos * QKVN + 4096 + kvh * DH_;
            acc = 0.f;
            for (int d = 0; d < 128; ++d) acc += qrow[d] * krow[d];
            acc *= SCALE;
        }
        sim[tid] = acc;
    }
    __syncthreads();
    if (tid == 0) {
        float m = sim[0];
        for (int j = 1; j < 65; ++j) m = fmaxf(m, sim[j]);
        float den = 0.f;
        for (int j = 0; j < 65; ++j) { float e = expf(sim[j] - m); p[j] = e; den += e; }
        inv_den = 1.f / den;
    }
    __syncthreads();
    float acc = 0.f;
    int lim = (s + 1 < 65) ? (s + 1) : 65;
    for (int j = 0; j < lim; ++j)
        acc += p[j] * qkv[(size_t)(s - j) * QKVN + 5120 + kvh * DH_ + tid];
    sout[(size_t)s * 4096 + qh * DH_ + tid] = acc * inv_den;
}

// ---------------------------------------------------------------------------
__global__ void combine_gate(float* __restrict__ cout, const float* __restrict__ fout,
                             const float* __restrict__ sout, const float* __restrict__ gates)
{
    int idx = blockIdx.x * blockDim.x + threadIdx.x;   // S*4096
    if (idx >= S_ * 4096) return;
    int h = (idx >> 7) & 31;
    int s = idx >> 12;
    float g0 = gates[(size_t)s * 96 + h * 3 + 0];
    float g1 = gates[(size_t)s * 96 + h * 3 + 1];
    float g2 = gates[(size_t)s * 96 + h * 3 + 2];
    cout[idx] = g0 * cout[idx] + g1 * fout[idx] + g2 * sout[idx];
}

// ---------------------------------------------------------------------------
extern "C" void kernel_launch(void* const* d_in, const int* in_sizes, int n_in,
                              void* d_out, int out_size, void* d_ws, size_t ws_size,
                              hipStream_t stream)
{
    const float* hidden = (const float*)d_in[0];
    const float* w_qkv  = (const float*)d_in[1];
    const float* w_o    = (const float*)d_in[2];
    const float* k_pos  = (const float*)d_in[3];
    const float* v_pos  = (const float*)d_in[4];
    const float* k_w1   = (const float*)d_in[5];
    const float* k_b1   = (const float*)d_in[6];
    const float* k_w2   = (const float*)d_in[7];
    const float* k_b2   = (const float*)d_in[8];
    const float* v_w1   = (const float*)d_in[9];
    const float* v_b1   = (const float*)d_in[10];
    const float* v_w2   = (const float*)d_in[11];
    const float* v_b2   = (const float*)d_in[12];
    const float* mem_kv = (const float*)d_in[13];
    const float* w_gate = (const float*)d_in[14];
    const float* b_gate = (const float*)d_in[15];
    float* out = (float*)d_out;

    float* ws = (float*)d_ws;
    size_t o = 0;
    float* qkv    = ws + o; o += (size_t)S_ * QKVN;
    float* ckin   = ws + o; o += (size_t)512 * CD_;
    float* cvin   = ws + o; o += (size_t)512 * CD_;
    float* h1     = ws + o; o += (size_t)512 * CD_;
    float* ckb    = ws + o; o += (size_t)512 * DH_;
    float* cvb    = ws + o; o += (size_t)512 * DH_;
    float* ckf    = ws + o; o += (size_t)KVH_ * 65 * DH_;
    float* cvf    = ws + o; o += (size_t)KVH_ * 65 * DH_;
    float* csim   = ws + o; o += (size_t)KVH_ * 4 * S_ * 65;
    float* coutb  = ws + o; o += (size_t)S_ * 4096;
    float* foutb  = ws + o; o += (size_t)S_ * 4096;
    float* soutb  = ws + o; o += (size_t)S_ * 4096;
    float* gatesb = ws + o; o += (size_t)S_ * 96;
    int*   selidx = (int*)(ws + o); o += (size_t)KVH_ * S_ * 5;
    int*   fsel   = (int*)(ws + o); o += (size_t)KVH_ * S_ * 4;

    // split-K partial buffer aliased on foutb (4,194,304 floats; foutb is only
    // written at step 12, after the last split-K reduce).
    float* P = foutb;

    // 1. qkv projection [1024,6144] — MFMA bf16x3, direct
    gemm_mfma<<<dim3(QKVN / 128, S_ / 128, 1), 256, 0, stream>>>(
        hidden, w_qkv, qkv, nullptr, nullptr, S_, QKVN, 4096, 4096, 0);

    // 2. gates [1024,96] — vector split-K=16 (N not a multiple of 128)
    gemm128<<<dim3(1, S_ / 128, 16), 256, 0, stream>>>(
        hidden, w_gate, nullptr, P, nullptr, S_, 96, 4096, 256, 0);
    reduce_slices<<<(S_ * 96 / 4 + 255) / 256, 256, 0, stream>>>(
        P, gatesb, b_gate, S_ * 96, 96, 16, 2);

    // 3. compress inputs
    build_cin<<<(KVH_ * S_ * DH_ + 255) / 256, 256, 0, stream>>>(qkv, k_pos, v_pos, ckin, cvin);

    // 4-7. compress MLPs: MLP1 via MFMA split-K=4, MLP2 via vector split-K
    gemm_mfma<<<dim3(CD_ / 128, 4, 4), 256, 0, stream>>>(
        ckin, k_w1, nullptr, P, nullptr, 512, CD_, CD_, 512, 0);
    reduce_slices<<<(512 * CD_ / 4 + 255) / 256, 256, 0, stream>>>(
        P, h1, k_b1, 512 * CD_, CD_, 4, 1);
    gemm128<<<dim3(1, 4, 16), 256, 0, stream>>>(
        h1, k_w2, nullptr, P, nullptr, 512, DH_, CD_, 128, 0);
    reduce_slices<<<(512 * DH_ / 4 + 255) / 256, 256, 0, stream>>>(
        P, ckb, k_b2, 512 * DH_, DH_, 16, 0);

    gemm_mfma<<<dim3(CD_ / 128, 4, 4), 256, 0, stream>>>(
        cvin, v_w1, nullptr, P, nullptr, 512, CD_, CD_, 512, 0);
    reduce_slices<<<(512 * CD_ / 4 + 255) / 256, 256, 0, stream>>>(
        P, h1, v_b1, 512 * CD_, CD_, 4, 1);
    gemm128<<<dim3(1, 4, 16), 256, 0, stream>>>(
        h1, v_w2, nullptr, P, nullptr, 512, DH_, CD_, 128, 0);
    reduce_slices<<<(512 * DH_ / 4 + 255) / 256, 256, 0, stream>>>(
        P, cvb, v_b2, 512 * DH_, DH_, 16, 0);

    // 8. prepend mem token
    assemble_c<<<(KVH_ * 65 * DH_ + 255) / 256, 256, 0, stream>>>(ckb, cvb, mem_kv, ckf, cvf);

    // 9. compressed attention (writes masked csim for importance)
    compress_attn<<<KVH_ * 4 * S_, 128, 0, stream>>>(qkv, ckf, cvf, csim, coutb);

    // 10. importance + top-k selection
    importance_topk<<<KVH_ * S_, 64, 0, stream>>>(csim, selidx, fsel);

    // 11. RoPE in place on q and k slices of qkv
    {
        int tot = S_ * H_ * 64 + S_ * KVH_ * 64;
        rope_inplace<<<(tot + 255) / 256, 256, 0, stream>>>(qkv);
    }

    // 12. fine (selected-block) attention
    fine_attn<<<KVH_ * 4 * S_, 128, 0, stream>>>(qkv, selidx, fsel, foutb);

    // 13. sliding-window attention
    sliding_attn<<<H_ * S_, 128, 0, stream>>>(qkv, soutb);

    // 14. gated combine into coutb
    combine_gate<<<(S_ * 4096 + 255) / 256, 256, 0, stream>>>(coutb, foutb, soutb, gatesb);

    // 15. output projection [1024,4096] — MFMA bf16x3, direct
    gemm_mfma<<<dim3(4096 / 128, S_ / 128, 1), 256, 0, stream>>>(
        coutb, w_o, out, nullptr, nullptr, S_, 4096, 4096, 4096, 0);
}